// Round 6
// baseline (857.202 us; speedup 1.0000x reference)
//
#include <hip/hip_runtime.h>

#define IN_FEAT 128
#define OUT_FEAT 64
#define LRELU_ALPHA 0.2f
#define BUK_SHIFT 8       // coarse bucket = src >> 8 (256 nodes/bucket)
#define BUK_SIZE 256
#define MAX_NBUK 512      // N <= 131072
#define BIN_PER_THREAD 32 // 8192 edges per bin block

typedef __attribute__((ext_vector_type(8))) short bf16x8;
typedef __attribute__((ext_vector_type(4))) float floatx4;

// fp32 -> bf16 bits, round-to-nearest-even (inputs are finite; no NaN guard)
__device__ __forceinline__ short f2bf(float f) {
  union { float f; unsigned u; } v; v.f = f;
  unsigned r = v.u + 0x7fff + ((v.u >> 16) & 1);
  return (short)(r >> 16);
}
__device__ __forceinline__ float bf2f(unsigned short s) {
  union { unsigned u; float f; } v; v.u = ((unsigned)s) << 16;
  return v.f;
}
__device__ __forceinline__ float elu(float v) {
  return v > 0.f ? v : __expf(v) - 1.f;
}

// ---------------------------------------------------------------------------
// Kernel 1: h = bf16(x) @ bf16(W) via MFMA 16x16x32. Block = 4 waves = 64 rows.
// Fused: s1 = h@a1, s2 = h@a2 (quad shuffle reduction). h stored as bf16 bits.
// ---------------------------------------------------------------------------
__global__ __launch_bounds__(256) void gemm_mfma_kernel(
    const float* __restrict__ x, const float* __restrict__ W,
    const float* __restrict__ a, unsigned short* __restrict__ h,
    float* __restrict__ s1, float* __restrict__ s2, int N) {
  __shared__ __align__(16) short Wt[64 * 136];  // W^T bf16, stride 136
  __shared__ float a_sh[2 * OUT_FEAT];

  if (threadIdx.x < 2 * OUT_FEAT) a_sh[threadIdx.x] = a[threadIdx.x];
  for (int i = threadIdx.x; i < IN_FEAT * OUT_FEAT; i += 256) {
    int k = i >> 6, n = i & 63;
    Wt[n * 136 + k] = f2bf(W[i]);
  }
  __syncthreads();

  int wave = threadIdx.x >> 6;
  int lane = threadIdx.x & 63;
  int l = lane & 15;
  int quad = lane >> 4;

  int row_base = blockIdx.x * 64 + wave * 16;
  int m = row_base + l;
  int m_c = m < N ? m : N - 1;

  bf16x8 bfrag[4][4];
#pragma unroll
  for (int kt = 0; kt < 4; ++kt)
#pragma unroll
    for (int nt = 0; nt < 4; ++nt)
      bfrag[kt][nt] = *(const bf16x8*)&Wt[(nt * 16 + l) * 136 + kt * 32 + quad * 8];

  floatx4 acc[4] = {floatx4{0,0,0,0}, floatx4{0,0,0,0}, floatx4{0,0,0,0}, floatx4{0,0,0,0}};
  const float* xrow = x + (size_t)m_c * IN_FEAT;
#pragma unroll
  for (int kt = 0; kt < 4; ++kt) {
    float4 xa = *(const float4*)(xrow + kt * 32 + quad * 8);
    float4 xb = *(const float4*)(xrow + kt * 32 + quad * 8 + 4);
    bf16x8 af;
    af[0] = f2bf(xa.x); af[1] = f2bf(xa.y); af[2] = f2bf(xa.z); af[3] = f2bf(xa.w);
    af[4] = f2bf(xb.x); af[5] = f2bf(xb.y); af[6] = f2bf(xb.z); af[7] = f2bf(xb.w);
#pragma unroll
    for (int nt = 0; nt < 4; ++nt)
      acc[nt] = __builtin_amdgcn_mfma_f32_16x16x32_bf16(af, bfrag[kt][nt], acc[nt], 0, 0, 0);
  }

  int out_row = row_base + quad * 4;
#pragma unroll
  for (int reg = 0; reg < 4; ++reg) {
    int r = out_row + reg;
    if (r < N) {
#pragma unroll
      for (int nt = 0; nt < 4; ++nt)
        h[(size_t)r * OUT_FEAT + nt * 16 + l] = (unsigned short)f2bf(acc[nt][reg]);
    }
  }

  float p1[4] = {0, 0, 0, 0}, p2[4] = {0, 0, 0, 0};
#pragma unroll
  for (int nt = 0; nt < 4; ++nt) {
    float a1v = a_sh[nt * 16 + l];
    float a2v = a_sh[OUT_FEAT + nt * 16 + l];
#pragma unroll
    for (int reg = 0; reg < 4; ++reg) {
      p1[reg] += acc[nt][reg] * a1v;
      p2[reg] += acc[nt][reg] * a2v;
    }
  }
#pragma unroll
  for (int off = 1; off < 16; off <<= 1) {
#pragma unroll
    for (int reg = 0; reg < 4; ++reg) {
      p1[reg] += __shfl_xor(p1[reg], off);
      p2[reg] += __shfl_xor(p2[reg], off);
    }
  }
  if (l < 4) {
    int r = out_row + l;
    if (r < N) {
      float v1 = l == 0 ? p1[0] : (l == 1 ? p1[1] : (l == 2 ? p1[2] : p1[3]));
      float v2 = l == 0 ? p2[0] : (l == 1 ? p2[1] : (l == 2 ? p2[2] : p2[3]));
      s1[r] = v1;
      s2[r] = v2;
    }
  }
}

// ---------------------------------------------------------------------------
// Coarse histogram over <=512 buckets: per-block LDS hist, then <=512 global
// atomics per block onto a 2KB array. No per-edge global atomics.
// ---------------------------------------------------------------------------
__global__ __launch_bounds__(256) void coarse_hist_kernel(
    const int* __restrict__ src, int* __restrict__ cbuk, int E) {
  __shared__ int lh[MAX_NBUK];
  int t = threadIdx.x;
  for (int i = t; i < MAX_NBUK; i += 256) lh[i] = 0;
  __syncthreads();
  for (int e = blockIdx.x * 256 + t; e < E; e += gridDim.x * 256)
    atomicAdd(&lh[src[e] >> BUK_SHIFT], 1);
  __syncthreads();
  for (int i = t; i < MAX_NBUK; i += 256)
    if (lh[i] > 0) atomicAdd(&cbuk[i], lh[i]);
}

// Exclusive scan of bucket counts -> buk_off (NB+1 entries) + bin cursors.
__global__ __launch_bounds__(512) void scan_buckets_kernel(
    const int* __restrict__ cbuk, int* __restrict__ buk_off,
    int* __restrict__ buk_cursor, int NB) {
  __shared__ int lds[MAX_NBUK];
  int t = threadIdx.x;
  if (t < NB) lds[t] = cbuk[t];
  __syncthreads();
  if (t == 0) {
    int run = 0;
    for (int i = 0; i < NB; ++i) { int v = lds[i]; lds[i] = run; run += v; }
    buk_off[NB] = run;  // == E
  }
  __syncthreads();
  if (t < NB) {
    buk_off[t] = lds[t];
    buk_cursor[t] = lds[t];
  }
}

// ---------------------------------------------------------------------------
// Bin by src>>8, fused edge-coefficient compute: ee = exp(-lrelu(s1[s]+s2[d]))
// computed ONCE per edge here (vs 32x redundantly in the aggregate).
// bukdata[pos] = { (s_local<<24) | d, ee }. Per-block LDS histogram + one
// global atomic per (block,bucket) -> ~21-record contiguous runs per bucket.
// ---------------------------------------------------------------------------
__global__ __launch_bounds__(256) void bin_kernel(
    const int* __restrict__ src, const int* __restrict__ dst,
    const float* __restrict__ s1, const float* __restrict__ s2,
    int* __restrict__ buk_cursor, int2* __restrict__ bukdata, int E) {
  __shared__ int lhist[MAX_NBUK];
  __shared__ int lbase[MAX_NBUK];
  int t = threadIdx.x;
  for (int i = t; i < MAX_NBUK; i += 256) lhist[i] = 0;
  __syncthreads();

  int base_e = blockIdx.x * (256 * BIN_PER_THREAD);
  int s[BIN_PER_THREAD], d[BIN_PER_THREAD];
#pragma unroll
  for (int j = 0; j < BIN_PER_THREAD; ++j) {
    int e = base_e + j * 256 + t;
    bool valid = e < E;
    s[j] = valid ? src[e] : 0;
    d[j] = valid ? dst[e] : 0;
    if (valid) atomicAdd(&lhist[s[j] >> BUK_SHIFT], 1);
  }
  __syncthreads();
  for (int i = t; i < MAX_NBUK; i += 256) {
    int c = lhist[i];
    lbase[i] = c > 0 ? atomicAdd(&buk_cursor[i], c) : 0;
    lhist[i] = 0;  // reuse as in-block cursor
  }
  __syncthreads();
#pragma unroll
  for (int j = 0; j < BIN_PER_THREAD; ++j) {
    int e = base_e + j * 256 + t;
    if (e < E) {
      float sc = s1[s[j]] + s2[d[j]];
      float ee = __expf(-(sc > 0.f ? sc : LRELU_ALPHA * sc));
      int b = s[j] >> BUK_SHIFT;
      int pos = lbase[b] + atomicAdd(&lhist[b], 1);
      bukdata[pos] = make_int2(((s[j] & (BUK_SIZE - 1)) << 24) | d[j],
                               __float_as_int(ee));
    }
  }
}

// ---------------------------------------------------------------------------
// Bucket aggregate: one 1024-thread block per bucket (256 nodes, ~4100 edges).
// 64KB LDS accumulator: plane E = acc[node*32 + col'], plane O = acc[8192 + ..]
// with col' = (c2 + node) & 31 swizzle -> ds_add_f32 is 2-way max (free).
// Pass A: rowsum via LDS atomics (region reused as acc after register stash).
// Pass B: half-wave per edge, gather h (ushort2), 2 LDS float atomics.
// Fused finalize: out = elu(acc / rowsum), coalesced float4 stores.
// ---------------------------------------------------------------------------
__global__ __launch_bounds__(1024) void bucket_aggregate_kernel(
    const int2* __restrict__ bukdata, const int* __restrict__ buk_off,
    const unsigned short* __restrict__ h, float* __restrict__ out, int N) {
  __shared__ float acc[16384];  // 64 KB; acc[0..255] doubles as rowsum in pass A
  int t = threadIdx.x;
  int buk = blockIdx.x;
  int beg = buk_off[buk];
  int end = buk_off[buk + 1];

  // ---- Pass A: rowsum[node] = sum(ee) ----
  if (t < BUK_SIZE) acc[t] = 0.f;
  __syncthreads();
  for (int i = beg + t; i < end; i += 1024) {
    int2 p = bukdata[i];
    atomicAdd(&acc[(unsigned)p.x >> 24], __int_as_float(p.y));
  }
  __syncthreads();

  int node = t >> 2;  // 4 threads per node for finalize
  int q = t & 3;      // 16-col group
  float r = acc[node];
  __syncthreads();

  // ---- Zero accumulator planes ----
#pragma unroll
  for (int k = 0; k < 4; ++k)
    *(float4*)&acc[t * 16 + k * 4] = make_float4(0.f, 0.f, 0.f, 0.f);
  __syncthreads();

  // ---- Pass B: accumulate ee * h[d] into LDS ----
  int wid = t >> 6;
  int lane = t & 63;
  int half = lane >> 5;
  int c2 = lane & 31;

  int i = beg + wid * 8;
  for (; i + 8 <= end; i += 16 * 8) {
#pragma unroll
    for (int j = 0; j < 4; ++j) {
      int2 p = bukdata[i + 2 * j + half];
      unsigned key = (unsigned)p.x;
      int sl = key >> 24;
      int d = key & 0xffffff;
      float ee = __int_as_float(p.y);
      unsigned v = *(const unsigned*)&h[d * OUT_FEAT + 2 * c2];
      int col = (c2 + sl) & 31;
      atomicAdd(&acc[sl * 32 + col], bf2f(v & 0xffff) * ee);
      atomicAdd(&acc[8192 + sl * 32 + col], bf2f(v >> 16) * ee);
    }
  }
  if (i < end) {  // this wave owns the final partial 8-block
    for (int k = i + half; k < end; k += 2) {
      int2 p = bukdata[k];
      unsigned key = (unsigned)p.x;
      int sl = key >> 24;
      int d = key & 0xffffff;
      float ee = __int_as_float(p.y);
      unsigned v = *(const unsigned*)&h[d * OUT_FEAT + 2 * c2];
      int col = (c2 + sl) & 31;
      atomicAdd(&acc[sl * 32 + col], bf2f(v & 0xffff) * ee);
      atomicAdd(&acc[8192 + sl * 32 + col], bf2f(v >> 16) * ee);
    }
  }
  __syncthreads();

  // ---- Finalize: out[node] = elu(acc / rowsum) ----
  int ng = (buk << BUK_SHIFT) + node;
  if (ng < N) {
    float rinv = 1.f / r;
#pragma unroll
    for (int mm = 0; mm < 4; ++mm) {
      int m0 = q * 8 + mm * 2;  // even-col pair index
      float e0 = acc[node * 32 + ((m0 + node) & 31)];
      float o0 = acc[8192 + node * 32 + ((m0 + node) & 31)];
      float e1 = acc[node * 32 + ((m0 + 1 + node) & 31)];
      float o1 = acc[8192 + node * 32 + ((m0 + 1 + node) & 31)];
      float4 f;
      f.x = elu(e0 * rinv);
      f.y = elu(o0 * rinv);
      f.z = elu(e1 * rinv);
      f.w = elu(o1 * rinv);
      *(float4*)&out[(size_t)ng * OUT_FEAT + q * 16 + mm * 4] = f;
    }
  }
}

extern "C" void kernel_launch(void* const* d_in, const int* in_sizes, int n_in,
                              void* d_out, int out_size, void* d_ws, size_t ws_size,
                              hipStream_t stream) {
  const float* x = (const float*)d_in[0];  // (N, 128) fp32
  const float* W = (const float*)d_in[1];  // (128, 64) fp32
  const float* a = (const float*)d_in[2];  // (1, 128) fp32
  const int* edge = (const int*)d_in[3];   // (2, E) int32

  const int N = in_sizes[0] / IN_FEAT;
  const int E = in_sizes[3] / 2;
  const int* src = edge;
  const int* dst = edge + E;

  float* out = (float*)d_out;  // (N, 64) fp32

  // Workspace layout (~27 MB)
  char* p = (char*)d_ws;
  unsigned short* h = (unsigned short*)p; p += (size_t)N * OUT_FEAT * sizeof(unsigned short);
  float* s1 = (float*)p;      p += (size_t)N * sizeof(float);
  float* s2 = (float*)p;      p += (size_t)N * sizeof(float);
  int* cbuk = (int*)p;        p += MAX_NBUK * sizeof(int);
  int* buk_off = (int*)p;     p += (MAX_NBUK + 1) * sizeof(int);
  int* buk_cursor = (int*)p;  p += MAX_NBUK * sizeof(int);
  int2* bukdata = (int2*)p;   p += (size_t)E * sizeof(int2);

  const int NB = (N + BUK_SIZE - 1) / BUK_SIZE;  // coarse buckets (391)

  hipMemsetAsync(cbuk, 0, MAX_NBUK * sizeof(int), stream);

  int grid_gemm = (N + 63) / 64;
  gemm_mfma_kernel<<<grid_gemm, 256, 0, stream>>>(x, W, a, h, s1, s2, N);

  coarse_hist_kernel<<<512, 256, 0, stream>>>(src, cbuk, E);
  scan_buckets_kernel<<<1, 512, 0, stream>>>(cbuk, buk_off, buk_cursor, NB);

  int grid_bin = (E + 256 * BIN_PER_THREAD - 1) / (256 * BIN_PER_THREAD);
  bin_kernel<<<grid_bin, 256, 0, stream>>>(src, dst, s1, s2, buk_cursor, bukdata, E);

  bucket_aggregate_kernel<<<NB, 1024, 0, stream>>>(bukdata, buk_off, h, out, N);
}

// Round 7
// 235.542 us; speedup vs baseline: 3.6393x; 3.6393x over previous
//
#include <hip/hip_runtime.h>

#define IN_FEAT 128
#define OUT_FEAT 64
#define LRELU_ALPHA 0.2f
#define BUK_SHIFT 8       // coarse bucket = src >> 8 (256 nodes/bucket)
#define BUK_SIZE 256
#define MAX_NBUK 512      // N <= 131072
#define BIN_PER_THREAD 16 // 4096 edges per bin block

typedef __attribute__((ext_vector_type(8))) short bf16x8;
typedef __attribute__((ext_vector_type(4))) float floatx4;

// fp32 -> bf16 bits, round-to-nearest-even (inputs are finite; no NaN guard)
__device__ __forceinline__ short f2bf(float f) {
  union { float f; unsigned u; } v; v.f = f;
  unsigned r = v.u + 0x7fff + ((v.u >> 16) & 1);
  return (short)(r >> 16);
}
__device__ __forceinline__ float bf2f(unsigned short s) {
  union { unsigned u; float f; } v; v.u = ((unsigned)s) << 16;
  return v.f;
}

// ---------------------------------------------------------------------------
// Kernel 1: h = bf16(x) @ bf16(W) via MFMA 16x16x32. Block = 4 waves = 64 rows.
// Fused: s1 = h@a1, s2 = h@a2 (quad shuffle reduction). h stored as bf16 bits.
// ---------------------------------------------------------------------------
__global__ __launch_bounds__(256) void gemm_mfma_kernel(
    const float* __restrict__ x, const float* __restrict__ W,
    const float* __restrict__ a, unsigned short* __restrict__ h,
    float* __restrict__ s1, float* __restrict__ s2, int N) {
  __shared__ __align__(16) short Wt[64 * 136];  // W^T bf16, stride 136
  __shared__ float a_sh[2 * OUT_FEAT];

  if (threadIdx.x < 2 * OUT_FEAT) a_sh[threadIdx.x] = a[threadIdx.x];
  for (int i = threadIdx.x; i < IN_FEAT * OUT_FEAT; i += 256) {
    int k = i >> 6, n = i & 63;
    Wt[n * 136 + k] = f2bf(W[i]);
  }
  __syncthreads();

  int wave = threadIdx.x >> 6;
  int lane = threadIdx.x & 63;
  int l = lane & 15;
  int quad = lane >> 4;

  int row_base = blockIdx.x * 64 + wave * 16;
  int m = row_base + l;
  int m_c = m < N ? m : N - 1;

  bf16x8 bfrag[4][4];
#pragma unroll
  for (int kt = 0; kt < 4; ++kt)
#pragma unroll
    for (int nt = 0; nt < 4; ++nt)
      bfrag[kt][nt] = *(const bf16x8*)&Wt[(nt * 16 + l) * 136 + kt * 32 + quad * 8];

  floatx4 acc[4] = {floatx4{0,0,0,0}, floatx4{0,0,0,0}, floatx4{0,0,0,0}, floatx4{0,0,0,0}};
  const float* xrow = x + (size_t)m_c * IN_FEAT;
#pragma unroll
  for (int kt = 0; kt < 4; ++kt) {
    float4 xa = *(const float4*)(xrow + kt * 32 + quad * 8);
    float4 xb = *(const float4*)(xrow + kt * 32 + quad * 8 + 4);
    bf16x8 af;
    af[0] = f2bf(xa.x); af[1] = f2bf(xa.y); af[2] = f2bf(xa.z); af[3] = f2bf(xa.w);
    af[4] = f2bf(xb.x); af[5] = f2bf(xb.y); af[6] = f2bf(xb.z); af[7] = f2bf(xb.w);
#pragma unroll
    for (int nt = 0; nt < 4; ++nt)
      acc[nt] = __builtin_amdgcn_mfma_f32_16x16x32_bf16(af, bfrag[kt][nt], acc[nt], 0, 0, 0);
  }

  int out_row = row_base + quad * 4;
#pragma unroll
  for (int reg = 0; reg < 4; ++reg) {
    int r = out_row + reg;
    if (r < N) {
#pragma unroll
      for (int nt = 0; nt < 4; ++nt)
        h[(size_t)r * OUT_FEAT + nt * 16 + l] = (unsigned short)f2bf(acc[nt][reg]);
    }
  }

  float p1[4] = {0, 0, 0, 0}, p2[4] = {0, 0, 0, 0};
#pragma unroll
  for (int nt = 0; nt < 4; ++nt) {
    float a1v = a_sh[nt * 16 + l];
    float a2v = a_sh[OUT_FEAT + nt * 16 + l];
#pragma unroll
    for (int reg = 0; reg < 4; ++reg) {
      p1[reg] += acc[nt][reg] * a1v;
      p2[reg] += acc[nt][reg] * a2v;
    }
  }
#pragma unroll
  for (int off = 1; off < 16; off <<= 1) {
#pragma unroll
    for (int reg = 0; reg < 4; ++reg) {
      p1[reg] += __shfl_xor(p1[reg], off);
      p2[reg] += __shfl_xor(p2[reg], off);
    }
  }
  if (l < 4) {
    int r = out_row + l;
    if (r < N) {
      float v1 = l == 0 ? p1[0] : (l == 1 ? p1[1] : (l == 2 ? p1[2] : p1[3]));
      float v2 = l == 0 ? p2[0] : (l == 1 ? p2[1] : (l == 2 ? p2[2] : p2[3]));
      s1[r] = v1;
      s2[r] = v2;
    }
  }
}

// ---------------------------------------------------------------------------
// Coarse histogram over <=512 buckets: per-block LDS hist, then <=512 global
// atomics per block onto a 2KB array. No per-edge global atomics.
// ---------------------------------------------------------------------------
__global__ __launch_bounds__(256) void coarse_hist_kernel(
    const int* __restrict__ src, int* __restrict__ cbuk, int E) {
  __shared__ int lh[MAX_NBUK];
  int t = threadIdx.x;
  for (int i = t; i < MAX_NBUK; i += 256) lh[i] = 0;
  __syncthreads();
  for (int e = blockIdx.x * 256 + t; e < E; e += gridDim.x * 256)
    atomicAdd(&lh[src[e] >> BUK_SHIFT], 1);
  __syncthreads();
  for (int i = t; i < MAX_NBUK; i += 256)
    if (lh[i] > 0) atomicAdd(&cbuk[i], lh[i]);
}

// Exclusive scan of bucket counts -> buk_off (NB+1 entries) + bin cursors.
__global__ __launch_bounds__(512) void scan_buckets_kernel(
    const int* __restrict__ cbuk, int* __restrict__ buk_off,
    int* __restrict__ buk_cursor, int NB) {
  __shared__ int lds[MAX_NBUK];
  int t = threadIdx.x;
  if (t < NB) lds[t] = cbuk[t];
  __syncthreads();
  if (t == 0) {
    int run = 0;
    for (int i = 0; i < NB; ++i) { int v = lds[i]; lds[i] = run; run += v; }
    buk_off[NB] = run;  // == E
  }
  __syncthreads();
  if (t < NB) {
    buk_off[t] = lds[t];
    buk_cursor[t] = lds[t];
  }
}

// ---------------------------------------------------------------------------
// Bin by src>>8, fused edge-coefficient: ee = exp(-lrelu(s1[s]+s2[d])) computed
// ONCE per edge here (round-5's node_aggregate recomputed it 32x/edge -> 68%
// VALUBusy). bukdata[pos] = { (s_local<<24)|dst, ee }. Per-block LDS histogram
// + one global atomic per (block,bucket) -> contiguous write runs per bucket.
// ---------------------------------------------------------------------------
__global__ __launch_bounds__(256) void bin_kernel(
    const int* __restrict__ src, const int* __restrict__ dst,
    const float* __restrict__ s1, const float* __restrict__ s2,
    int* __restrict__ buk_cursor, int2* __restrict__ bukdata, int E) {
  __shared__ int lhist[MAX_NBUK];
  __shared__ int lbase[MAX_NBUK];
  int t = threadIdx.x;
  for (int i = t; i < MAX_NBUK; i += 256) lhist[i] = 0;
  __syncthreads();

  int base_e = blockIdx.x * (256 * BIN_PER_THREAD);
  int s[BIN_PER_THREAD], d[BIN_PER_THREAD];
#pragma unroll
  for (int j = 0; j < BIN_PER_THREAD; ++j) {
    int e = base_e + j * 256 + t;
    bool valid = e < E;
    s[j] = valid ? src[e] : 0;
    d[j] = valid ? dst[e] : 0;
    if (valid) atomicAdd(&lhist[s[j] >> BUK_SHIFT], 1);
  }
  __syncthreads();
  for (int i = t; i < MAX_NBUK; i += 256) {
    int c = lhist[i];
    lbase[i] = c > 0 ? atomicAdd(&buk_cursor[i], c) : 0;
    lhist[i] = 0;  // reuse as in-block cursor
  }
  __syncthreads();
#pragma unroll
  for (int j = 0; j < BIN_PER_THREAD; ++j) {
    int e = base_e + j * 256 + t;
    if (e < E) {
      float sc = s1[s[j]] + s2[d[j]];
      float ee = __expf(-(sc > 0.f ? sc : LRELU_ALPHA * sc));
      int b = s[j] >> BUK_SHIFT;
      int pos = lbase[b] + atomicAdd(&lhist[b], 1);
      bukdata[pos] = make_int2(((s[j] & (BUK_SIZE - 1)) << 24) | d[j],
                               __float_as_int(ee));
    }
  }
}

// ---------------------------------------------------------------------------
// Fine sort within each bucket: one 256-thread block per bucket (256 nodes,
// ~4100 edges). LDS fine histogram + block scan -> coalesced row_start/counts;
// LDS-cursor scatter of rec (int2{dst,ee}) into a ~33KB window (L2-resident).
// No per-edge global atomics.
// ---------------------------------------------------------------------------
__global__ __launch_bounds__(256) void bucket_build_kernel(
    const int2* __restrict__ bukdata, const int* __restrict__ buk_off,
    int* __restrict__ row_start, int* __restrict__ counts,
    int2* __restrict__ rec, int N) {
  __shared__ int lhist[BUK_SIZE];
  __shared__ int lcur[BUK_SIZE];
  __shared__ int wtot[4];
  int t = threadIdx.x;
  int buk = blockIdx.x;
  int beg = buk_off[buk];
  int end = buk_off[buk + 1];

  lhist[t] = 0;
  __syncthreads();
  for (int i = beg + t; i < end; i += 256)
    atomicAdd(&lhist[(unsigned)bukdata[i].x >> 24], 1);
  __syncthreads();

  // Block-wide exclusive scan over 256 counters (1 per thread).
  int v0 = lhist[t];
  int lane = t & 63, w = t >> 6;
  int xs = v0;
#pragma unroll
  for (int off = 1; off < 64; off <<= 1) {
    int y = __shfl_up(xs, off);
    if (lane >= off) xs += y;
  }
  if (lane == 63) wtot[w] = xs;
  __syncthreads();
  int woff = 0;
  for (int i = 0; i < w; ++i) woff += wtot[i];
  int excl = woff + (xs - v0);

  int node = (buk << BUK_SHIFT) + t;
  if (node < N) { row_start[node] = beg + excl; counts[node] = v0; }
  lcur[t] = excl;
  __syncthreads();

  for (int i = beg + t; i < end; i += 256) {
    int2 p = bukdata[i];
    unsigned key = (unsigned)p.x;
    int pos = beg + atomicAdd(&lcur[key >> 24], 1);
    rec[pos] = make_int2(key & 0xffffff, p.y);
  }
}

// ---------------------------------------------------------------------------
// Kernel 3: atomic-free aggregate. One wave per node; bf16 h row = 128B =
// 32 lanes x ushort2; the two wave-halves process alternating edges (8 gathers
// in flight with the x4 unroll). ee precomputed (no exp, no s2 gather here).
// Cross-half shfl_xor(32) reduce. Fused finalize: out = elu(acc / rowsum).
// ---------------------------------------------------------------------------
__global__ __launch_bounds__(256) void node_aggregate_kernel(
    const int2* __restrict__ rec, const int* __restrict__ row_start,
    const int* __restrict__ counts, const unsigned short* __restrict__ h,
    float* __restrict__ out, int N) {
  int tid = blockIdx.x * 256 + threadIdx.x;
  int n = tid >> 6;
  if (n >= N) return;
  int lane = threadIdx.x & 63;
  int half = lane >> 5;
  int c2 = lane & 31;

  int start = row_start[n];
  int cnt = counts[n];
  float ax = 0.f, ay = 0.f, rs = 0.f;

  int i = 0;
  for (; i + 8 <= cnt; i += 8) {
    int b0 = start + i + half;
    int2 r0 = rec[b0], r1 = rec[b0 + 2], r2 = rec[b0 + 4], r3 = rec[b0 + 6];
    unsigned v0 = *(const unsigned*)&h[(size_t)r0.x * OUT_FEAT + 2 * c2];
    unsigned v1 = *(const unsigned*)&h[(size_t)r1.x * OUT_FEAT + 2 * c2];
    unsigned v2 = *(const unsigned*)&h[(size_t)r2.x * OUT_FEAT + 2 * c2];
    unsigned v3 = *(const unsigned*)&h[(size_t)r3.x * OUT_FEAT + 2 * c2];
    float e0 = __int_as_float(r0.y), e1 = __int_as_float(r1.y);
    float e2 = __int_as_float(r2.y), e3 = __int_as_float(r3.y);
    rs += (e0 + e1) + (e2 + e3);
    ax += e0 * bf2f(v0 & 0xffff) + e1 * bf2f(v1 & 0xffff) +
          e2 * bf2f(v2 & 0xffff) + e3 * bf2f(v3 & 0xffff);
    ay += e0 * bf2f(v0 >> 16) + e1 * bf2f(v1 >> 16) +
          e2 * bf2f(v2 >> 16) + e3 * bf2f(v3 >> 16);
  }
  for (; i + 2 <= cnt; i += 2) {
    int2 r = rec[start + i + half];
    unsigned v = *(const unsigned*)&h[(size_t)r.x * OUT_FEAT + 2 * c2];
    float ee = __int_as_float(r.y);
    rs += ee;
    ax += ee * bf2f(v & 0xffff);
    ay += ee * bf2f(v >> 16);
  }
  if (i < cnt && half == 0) {
    int2 r = rec[start + i];
    unsigned v = *(const unsigned*)&h[(size_t)r.x * OUT_FEAT + 2 * c2];
    float ee = __int_as_float(r.y);
    rs += ee;
    ax += ee * bf2f(v & 0xffff);
    ay += ee * bf2f(v >> 16);
  }

  rs += __shfl_xor(rs, 32);
  ax += __shfl_xor(ax, 32);
  ay += __shfl_xor(ay, 32);

  if (half == 0) {
    float vx = ax / rs, vy = ay / rs;
    vx = vx > 0.f ? vx : __expf(vx) - 1.f;
    vy = vy > 0.f ? vy : __expf(vy) - 1.f;
    *(float2*)&out[(size_t)n * OUT_FEAT + 2 * c2] = make_float2(vx, vy);
  }
}

extern "C" void kernel_launch(void* const* d_in, const int* in_sizes, int n_in,
                              void* d_out, int out_size, void* d_ws, size_t ws_size,
                              hipStream_t stream) {
  const float* x = (const float*)d_in[0];  // (N, 128) fp32
  const float* W = (const float*)d_in[1];  // (128, 64) fp32
  const float* a = (const float*)d_in[2];  // (1, 128) fp32
  const int* edge = (const int*)d_in[3];   // (2, E) int32

  const int N = in_sizes[0] / IN_FEAT;
  const int E = in_sizes[3] / 2;
  const int* src = edge;
  const int* dst = edge + E;

  float* out = (float*)d_out;  // (N, 64) fp32

  // Workspace layout (~40 MB)
  char* p = (char*)d_ws;
  unsigned short* h = (unsigned short*)p; p += (size_t)N * OUT_FEAT * sizeof(unsigned short);
  float* s1 = (float*)p;      p += (size_t)N * sizeof(float);
  float* s2 = (float*)p;      p += (size_t)N * sizeof(float);
  int* counts = (int*)p;      p += (size_t)N * sizeof(int);
  int* row_start = (int*)p;   p += (size_t)N * sizeof(int);
  int* cbuk = (int*)p;        p += MAX_NBUK * sizeof(int);
  int* buk_off = (int*)p;     p += (MAX_NBUK + 1) * sizeof(int);
  int* buk_cursor = (int*)p;  p += MAX_NBUK * sizeof(int);
  int2* rec = (int2*)p;       p += (size_t)E * sizeof(int2);
  int2* bukdata = (int2*)p;   p += (size_t)E * sizeof(int2);

  const int NB = (N + BUK_SIZE - 1) / BUK_SIZE;  // coarse buckets (391)

  hipMemsetAsync(cbuk, 0, MAX_NBUK * sizeof(int), stream);

  int grid_gemm = (N + 63) / 64;
  gemm_mfma_kernel<<<grid_gemm, 256, 0, stream>>>(x, W, a, h, s1, s2, N);

  coarse_hist_kernel<<<512, 256, 0, stream>>>(src, cbuk, E);
  scan_buckets_kernel<<<1, 512, 0, stream>>>(cbuk, buk_off, buk_cursor, NB);

  int grid_bin = (E + 256 * BIN_PER_THREAD - 1) / (256 * BIN_PER_THREAD);
  bin_kernel<<<grid_bin, 256, 0, stream>>>(src, dst, s1, s2, buk_cursor, bukdata, E);
  bucket_build_kernel<<<NB, 256, 0, stream>>>(bukdata, buk_off, row_start, counts, rec, N);

  int grid_rows = (N * OUT_FEAT + 255) / 256;
  node_aggregate_kernel<<<grid_rows, 256, 0, stream>>>(rec, row_start, counts, h, out, N);
}

// Round 8
// 222.373 us; speedup vs baseline: 3.8548x; 1.0592x over previous
//
#include <hip/hip_runtime.h>

#define IN_FEAT 128
#define OUT_FEAT 64
#define LRELU_ALPHA 0.2f
#define BUK_SHIFT 7        // coarse bucket = src >> 7 (128 nodes/bucket)
#define BUK_SIZE 128
#define MAX_NBUK 1024      // N <= 131072
#define D_BITS 17          // dst < 2^17 (N <= 131072): pk = (sl<<17)|dst
#define D_MASK 0x1FFFF
#define BIN_PER_THREAD 32  // 8192 edges per bin block
#define CAP 2560           // LDS record capacity per chunk (mean bucket ~2046)
#define STAGE_MAX 5        // CAP / 512

typedef __attribute__((ext_vector_type(8))) short bf16x8;
typedef __attribute__((ext_vector_type(4))) float floatx4;

// fp32 -> bf16 bits, round-to-nearest-even (inputs are finite; no NaN guard)
__device__ __forceinline__ short f2bf(float f) {
  union { float f; unsigned u; } v; v.f = f;
  unsigned r = v.u + 0x7fff + ((v.u >> 16) & 1);
  return (short)(r >> 16);
}
__device__ __forceinline__ float bf2f(unsigned short s) {
  union { unsigned u; float f; } v; v.u = ((unsigned)s) << 16;
  return v.f;
}

// ---------------------------------------------------------------------------
// Kernel 1: h = bf16(x) @ bf16(W) via MFMA 16x16x32. Block = 4 waves = 64 rows.
// Fused: s1 = h@a1, s2 = h@a2 (quad shuffle reduction). h stored as bf16 bits.
// ---------------------------------------------------------------------------
__global__ __launch_bounds__(256) void gemm_mfma_kernel(
    const float* __restrict__ x, const float* __restrict__ W,
    const float* __restrict__ a, unsigned short* __restrict__ h,
    float* __restrict__ s1, float* __restrict__ s2, int N) {
  __shared__ __align__(16) short Wt[64 * 136];  // W^T bf16, stride 136
  __shared__ float a_sh[2 * OUT_FEAT];

  if (threadIdx.x < 2 * OUT_FEAT) a_sh[threadIdx.x] = a[threadIdx.x];
  for (int i = threadIdx.x; i < IN_FEAT * OUT_FEAT; i += 256) {
    int k = i >> 6, n = i & 63;
    Wt[n * 136 + k] = f2bf(W[i]);
  }
  __syncthreads();

  int wave = threadIdx.x >> 6;
  int lane = threadIdx.x & 63;
  int l = lane & 15;
  int quad = lane >> 4;

  int row_base = blockIdx.x * 64 + wave * 16;
  int m = row_base + l;
  int m_c = m < N ? m : N - 1;

  bf16x8 bfrag[4][4];
#pragma unroll
  for (int kt = 0; kt < 4; ++kt)
#pragma unroll
    for (int nt = 0; nt < 4; ++nt)
      bfrag[kt][nt] = *(const bf16x8*)&Wt[(nt * 16 + l) * 136 + kt * 32 + quad * 8];

  floatx4 acc[4] = {floatx4{0,0,0,0}, floatx4{0,0,0,0}, floatx4{0,0,0,0}, floatx4{0,0,0,0}};
  const float* xrow = x + (size_t)m_c * IN_FEAT;
#pragma unroll
  for (int kt = 0; kt < 4; ++kt) {
    float4 xa = *(const float4*)(xrow + kt * 32 + quad * 8);
    float4 xb = *(const float4*)(xrow + kt * 32 + quad * 8 + 4);
    bf16x8 af;
    af[0] = f2bf(xa.x); af[1] = f2bf(xa.y); af[2] = f2bf(xa.z); af[3] = f2bf(xa.w);
    af[4] = f2bf(xb.x); af[5] = f2bf(xb.y); af[6] = f2bf(xb.z); af[7] = f2bf(xb.w);
#pragma unroll
    for (int nt = 0; nt < 4; ++nt)
      acc[nt] = __builtin_amdgcn_mfma_f32_16x16x32_bf16(af, bfrag[kt][nt], acc[nt], 0, 0, 0);
  }

  int out_row = row_base + quad * 4;
#pragma unroll
  for (int reg = 0; reg < 4; ++reg) {
    int r = out_row + reg;
    if (r < N) {
#pragma unroll
      for (int nt = 0; nt < 4; ++nt)
        h[(size_t)r * OUT_FEAT + nt * 16 + l] = (unsigned short)f2bf(acc[nt][reg]);
    }
  }

  float p1[4] = {0, 0, 0, 0}, p2[4] = {0, 0, 0, 0};
#pragma unroll
  for (int nt = 0; nt < 4; ++nt) {
    float a1v = a_sh[nt * 16 + l];
    float a2v = a_sh[OUT_FEAT + nt * 16 + l];
#pragma unroll
    for (int reg = 0; reg < 4; ++reg) {
      p1[reg] += acc[nt][reg] * a1v;
      p2[reg] += acc[nt][reg] * a2v;
    }
  }
#pragma unroll
  for (int off = 1; off < 16; off <<= 1) {
#pragma unroll
    for (int reg = 0; reg < 4; ++reg) {
      p1[reg] += __shfl_xor(p1[reg], off);
      p2[reg] += __shfl_xor(p2[reg], off);
    }
  }
  if (l < 4) {
    int r = out_row + l;
    if (r < N) {
      float v1 = l == 0 ? p1[0] : (l == 1 ? p1[1] : (l == 2 ? p1[2] : p1[3]));
      float v2 = l == 0 ? p2[0] : (l == 1 ? p2[1] : (l == 2 ? p2[2] : p2[3]));
      s1[r] = v1;
      s2[r] = v2;
    }
  }
}

// ---------------------------------------------------------------------------
// Coarse histogram over <=1024 buckets: per-block LDS hist, then <=1024 global
// atomics per block onto a 4KB array. No per-edge global atomics.
// ---------------------------------------------------------------------------
__global__ __launch_bounds__(256) void coarse_hist_kernel(
    const int* __restrict__ src, int* __restrict__ cbuk, int E) {
  __shared__ int lh[MAX_NBUK];
  int t = threadIdx.x;
  for (int i = t; i < MAX_NBUK; i += 256) lh[i] = 0;
  __syncthreads();
  for (int e = blockIdx.x * 256 + t; e < E; e += gridDim.x * 256)
    atomicAdd(&lh[src[e] >> BUK_SHIFT], 1);
  __syncthreads();
  for (int i = t; i < MAX_NBUK; i += 256)
    if (lh[i] > 0) atomicAdd(&cbuk[i], lh[i]);
}

// Exclusive scan of bucket counts -> buk_off (NB+1 entries) + bin cursors.
__global__ __launch_bounds__(1024) void scan_buckets_kernel(
    const int* __restrict__ cbuk, int* __restrict__ buk_off,
    int* __restrict__ buk_cursor, int NB) {
  __shared__ int lds[MAX_NBUK];
  int t = threadIdx.x;
  if (t < NB) lds[t] = cbuk[t];
  __syncthreads();
  if (t == 0) {
    int run = 0;
    for (int i = 0; i < NB; ++i) { int v = lds[i]; lds[i] = run; run += v; }
    buk_off[NB] = run;  // == E
  }
  __syncthreads();
  if (t < NB) {
    buk_off[t] = lds[t];
    buk_cursor[t] = lds[t];
  }
}

// ---------------------------------------------------------------------------
// Bin by src>>7. Pure routing: bukdata[pos] = (sl<<17)|dst, 4B/edge (6.4MB).
// Per-block LDS histogram + one global atomic per (block,bucket) ->
// contiguous ~42B write runs per bucket (L2-merged).
// ---------------------------------------------------------------------------
__global__ __launch_bounds__(256) void bin_kernel(
    const int* __restrict__ src, const int* __restrict__ dst,
    int* __restrict__ buk_cursor, int* __restrict__ bukdata, int E) {
  __shared__ int lhist[MAX_NBUK];
  __shared__ int lbase[MAX_NBUK];
  int t = threadIdx.x;
  for (int i = t; i < MAX_NBUK; i += 256) lhist[i] = 0;
  __syncthreads();

  int base_e = blockIdx.x * (256 * BIN_PER_THREAD);
  int s[BIN_PER_THREAD], d[BIN_PER_THREAD];
#pragma unroll
  for (int j = 0; j < BIN_PER_THREAD; ++j) {
    int e = base_e + j * 256 + t;
    bool valid = e < E;
    s[j] = valid ? src[e] : 0;
    d[j] = valid ? dst[e] : 0;
    if (valid) atomicAdd(&lhist[s[j] >> BUK_SHIFT], 1);
  }
  __syncthreads();
  for (int i = t; i < MAX_NBUK; i += 256) {
    int c = lhist[i];
    lbase[i] = c > 0 ? atomicAdd(&buk_cursor[i], c) : 0;
    lhist[i] = 0;  // reuse as in-block cursor
  }
  __syncthreads();
#pragma unroll
  for (int j = 0; j < BIN_PER_THREAD; ++j) {
    int e = base_e + j * 256 + t;
    if (e < E) {
      int b = s[j] >> BUK_SHIFT;
      int pos = lbase[b] + atomicAdd(&lhist[b], 1);
      bukdata[pos] = ((s[j] & (BUK_SIZE - 1)) << D_BITS) | d[j];
    }
  }
}

// ---------------------------------------------------------------------------
// Fused sort+aggregate: one 512-thread block (8 waves) per 128-node bucket
// (~2048 edges). Per chunk (<=CAP records): stage packed edges in registers,
// LDS histogram (int atomics, ~2K/block - cheap, unlike round 6's 205M
// ds_add_f32), block scan, scatter {dst,ee} into LDS sorted by node; ee =
// exp(-lrelu(s1+s2)) computed ONCE per edge here (s1 bucket-preloaded in LDS,
// s2 400KB L2-resident). Then each wave aggregates its 16 nodes from
// LDS-resident records: broadcast ds_read + coalesced 128B h gather (the two
// wave-halves take alternating edges, 8 gathers in flight). Fused finalize.
// Replaces bucket_build + node_aggregate: no rec/row_start/counts arrays,
// no 25.6MB rec round-trip.
// ---------------------------------------------------------------------------
__global__ __launch_bounds__(512) void bucket_sort_aggregate_kernel(
    const int* __restrict__ bukdata, const int* __restrict__ buk_off,
    const float* __restrict__ s1, const float* __restrict__ s2,
    const unsigned short* __restrict__ h, float* __restrict__ out, int N) {
  __shared__ float s1sh[BUK_SIZE];
  __shared__ int lhist[BUK_SIZE];
  __shared__ int loffs[BUK_SIZE];
  __shared__ int lcur[BUK_SIZE];
  __shared__ int wtot[2];
  __shared__ int2 lrec[CAP];  // 20KB

  int t = threadIdx.x;
  int buk = blockIdx.x;
  int beg = buk_off[buk];
  int end = buk_off[buk + 1];
  int node_base = buk << BUK_SHIFT;

  if (t < BUK_SIZE) {
    int ng = node_base + t;
    s1sh[t] = ng < N ? s1[ng] : 0.f;
  }

  int wid = t >> 6;      // wave 0..7; owns nodes wid, wid+8, ..., wid+120
  int lane = t & 63;
  int half = lane >> 5;
  int c2 = lane & 31;

  float ax[16], ay[16], rs[16];
#pragma unroll
  for (int j = 0; j < 16; ++j) { ax[j] = 0.f; ay[j] = 0.f; rs[j] = 0.f; }

  for (int cbeg = beg; cbeg < end; cbeg += CAP) {
    int cnt = min(end - cbeg, CAP);

    if (t < BUK_SIZE) lhist[t] = 0;
    __syncthreads();  // also covers s1sh on first chunk

    // ---- Stage: load packed edges, compute ee once/edge, LDS histogram ----
    int dreg[STAGE_MAX];
    int slreg[STAGE_MAX];
    float ereg[STAGE_MAX];
#pragma unroll
    for (int j = 0; j < STAGE_MAX; ++j) {
      int i = t + j * 512;
      bool v = i < cnt;
      int pk = v ? bukdata[cbeg + i] : 0;
      slreg[j] = pk >> D_BITS;
      dreg[j] = pk & D_MASK;
      float sc = s1sh[slreg[j]] + (v ? s2[dreg[j]] : 0.f);
      ereg[j] = __expf(-(sc > 0.f ? sc : LRELU_ALPHA * sc));
      if (v) atomicAdd(&lhist[slreg[j]], 1);
    }
    __syncthreads();

    // ---- Block scan over 128 counters (threads 0..127, 2 waves) ----
    int hv = (t < BUK_SIZE) ? lhist[t] : 0;
    int xs = hv;
#pragma unroll
    for (int off = 1; off < 64; off <<= 1) {
      int y = __shfl_up(xs, off);
      if (lane >= off) xs += y;
    }
    if (t < BUK_SIZE && lane == 63) wtot[t >> 6] = xs;
    __syncthreads();
    if (t < BUK_SIZE) {
      int base = (t >> 6) ? wtot[0] : 0;
      int excl = base + xs - hv;
      loffs[t] = excl;
      lcur[t] = excl;
    }
    __syncthreads();

    // ---- Scatter into LDS, sorted by node ----
#pragma unroll
    for (int j = 0; j < STAGE_MAX; ++j) {
      int i = t + j * 512;
      if (i < cnt) {
        int pos = atomicAdd(&lcur[slreg[j]], 1);
        lrec[pos] = make_int2(dreg[j], __float_as_int(ereg[j]));
      }
    }
    __syncthreads();

    // ---- Aggregate: wave walks its 16 nodes' LDS-contiguous records ----
#pragma unroll
    for (int nn = 0; nn < 16; ++nn) {
      int nl = wid + nn * 8;
      int o = loffs[nl];
      int c = lhist[nl];
      int k = 0;
      for (; k + 8 <= c; k += 8) {
#pragma unroll
        for (int j = 0; j < 4; ++j) {
          int2 r = lrec[o + k + 2 * j + half];  // LDS broadcast per half
          float ee = __int_as_float(r.y);
          unsigned v = *(const unsigned*)&h[r.x * OUT_FEAT + 2 * c2];
          rs[nn] += ee;
          ax[nn] += ee * bf2f(v & 0xffff);
          ay[nn] += ee * bf2f(v >> 16);
        }
      }
      for (int m = k + half; m < c; m += 2) {
        int2 r = lrec[o + m];
        float ee = __int_as_float(r.y);
        unsigned v = *(const unsigned*)&h[r.x * OUT_FEAT + 2 * c2];
        rs[nn] += ee;
        ax[nn] += ee * bf2f(v & 0xffff);
        ay[nn] += ee * bf2f(v >> 16);
      }
    }
    __syncthreads();  // protect lhist/loffs/lrec before next chunk
  }

  // ---- Finalize: cross-half reduce, out = elu(acc / rowsum) ----
#pragma unroll
  for (int nn = 0; nn < 16; ++nn) {
    float r = rs[nn] + __shfl_xor(rs[nn], 32);
    float xv = ax[nn] + __shfl_xor(ax[nn], 32);
    float yv = ay[nn] + __shfl_xor(ay[nn], 32);
    int ng = node_base + wid + nn * 8;
    if (ng < N && half == 0) {
      float vx = xv / r, vy = yv / r;
      vx = vx > 0.f ? vx : __expf(vx) - 1.f;
      vy = vy > 0.f ? vy : __expf(vy) - 1.f;
      *(float2*)&out[(size_t)ng * OUT_FEAT + 2 * c2] = make_float2(vx, vy);
    }
  }
}

extern "C" void kernel_launch(void* const* d_in, const int* in_sizes, int n_in,
                              void* d_out, int out_size, void* d_ws, size_t ws_size,
                              hipStream_t stream) {
  const float* x = (const float*)d_in[0];  // (N, 128) fp32
  const float* W = (const float*)d_in[1];  // (128, 64) fp32
  const float* a = (const float*)d_in[2];  // (1, 128) fp32
  const int* edge = (const int*)d_in[3];   // (2, E) int32

  const int N = in_sizes[0] / IN_FEAT;
  const int E = in_sizes[3] / 2;
  const int* src = edge;
  const int* dst = edge + E;

  float* out = (float*)d_out;  // (N, 64) fp32

  // Workspace layout (~21 MB)
  char* p = (char*)d_ws;
  unsigned short* h = (unsigned short*)p; p += (size_t)N * OUT_FEAT * sizeof(unsigned short);
  float* s1 = (float*)p;      p += (size_t)N * sizeof(float);
  float* s2 = (float*)p;      p += (size_t)N * sizeof(float);
  int* cbuk = (int*)p;        p += MAX_NBUK * sizeof(int);
  int* buk_off = (int*)p;     p += (MAX_NBUK + 1) * sizeof(int);
  int* buk_cursor = (int*)p;  p += MAX_NBUK * sizeof(int);
  int* bukdata = (int*)p;     p += (size_t)E * sizeof(int);

  const int NB = (N + BUK_SIZE - 1) / BUK_SIZE;  // 782 buckets

  hipMemsetAsync(cbuk, 0, MAX_NBUK * sizeof(int), stream);

  int grid_gemm = (N + 63) / 64;
  gemm_mfma_kernel<<<grid_gemm, 256, 0, stream>>>(x, W, a, h, s1, s2, N);

  coarse_hist_kernel<<<512, 256, 0, stream>>>(src, cbuk, E);
  scan_buckets_kernel<<<1, 1024, 0, stream>>>(cbuk, buk_off, buk_cursor, NB);

  int grid_bin = (E + 256 * BIN_PER_THREAD - 1) / (256 * BIN_PER_THREAD);
  bin_kernel<<<grid_bin, 256, 0, stream>>>(src, dst, buk_cursor, bukdata, E);

  bucket_sort_aggregate_kernel<<<NB, 512, 0, stream>>>(bukdata, buk_off, s1, s2, h, out, N);
}